// Round 1
// baseline (34.200 us; speedup 1.0000x reference)
//
#include <hip/hip_runtime.h>

// RGlayer closed form:
//   u   = normalize(f[b,:,2X,2Y])            (coarse select + unit spin)
//   out = v + u * (1 - |v|^2) / (1 + u.v)    per fine pixel v = f[b,:,x,y]
// Derivation: R = I + A + A2 with A = u v^T - v u^T, A2 = A A /(1+u.v);
// out = R^T u collapses algebraically using |u| = 1.

#define H 512
#define W 512
#define HW (512 * 512)

__global__ __launch_bounds__(256) void rg_kernel(const float* __restrict__ f,
                                                 float* __restrict__ out) {
    int t = blockIdx.x * blockDim.x + threadIdx.x;
    // t -> (b, X, Yq): b in [0,32), X in [0,256) coarse row, Yq in [0,128) float4 col
    int Yq = t & 127;
    int X  = (t >> 7) & 255;
    int b  = t >> 15;

    const float* fb = f + (size_t)b * 3 * HW;
    float*       ob = out + (size_t)b * 3 * HW;
    size_t off = (size_t)(2 * X) * W + 4 * Yq;

    float4 top[3], bot[3];
#pragma unroll
    for (int s = 0; s < 3; ++s) {
        const float* p = fb + (size_t)s * HW + off;
        top[s] = *reinterpret_cast<const float4*>(p);
        bot[s] = *reinterpret_cast<const float4*>(p + W);
    }

    // Two coarse columns per float4: u_left from .x, u_right from .z (top row)
    float a0 = top[0].x, a1 = top[1].x, a2 = top[2].x;
    float ia = rsqrtf(fmaf(a0, a0, fmaf(a1, a1, a2 * a2)));
    float uL0 = a0 * ia, uL1 = a1 * ia, uL2 = a2 * ia;

    float c0 = top[0].z, c1 = top[1].z, c2 = top[2].z;
    float ic = rsqrtf(fmaf(c0, c0, fmaf(c1, c1, c2 * c2)));
    float uR0 = c0 * ic, uR1 = c1 * ic, uR2 = c2 * ic;

    auto comp = [&](float u0, float u1, float u2,
                    float v0, float v1, float v2,
                    float& o0, float& o1, float& o2) {
        float d  = fmaf(u0, v0, fmaf(u1, v1, u2 * v2));
        float vv = fmaf(v0, v0, fmaf(v1, v1, v2 * v2));
        float s  = (1.0f - vv) / (1.0f + d);
        o0 = fmaf(u0, s, v0);
        o1 = fmaf(u1, s, v1);
        o2 = fmaf(u2, s, v2);
    };

    float4 ot[3], obt[3];
    comp(uL0, uL1, uL2, top[0].x, top[1].x, top[2].x, ot[0].x, ot[1].x, ot[2].x);
    comp(uL0, uL1, uL2, top[0].y, top[1].y, top[2].y, ot[0].y, ot[1].y, ot[2].y);
    comp(uR0, uR1, uR2, top[0].z, top[1].z, top[2].z, ot[0].z, ot[1].z, ot[2].z);
    comp(uR0, uR1, uR2, top[0].w, top[1].w, top[2].w, ot[0].w, ot[1].w, ot[2].w);

    comp(uL0, uL1, uL2, bot[0].x, bot[1].x, bot[2].x, obt[0].x, obt[1].x, obt[2].x);
    comp(uL0, uL1, uL2, bot[0].y, bot[1].y, bot[2].y, obt[0].y, obt[1].y, obt[2].y);
    comp(uR0, uR1, uR2, bot[0].z, bot[1].z, bot[2].z, obt[0].z, obt[1].z, obt[2].z);
    comp(uR0, uR1, uR2, bot[0].w, bot[1].w, bot[2].w, obt[0].w, obt[1].w, obt[2].w);

#pragma unroll
    for (int s = 0; s < 3; ++s) {
        float* p = ob + (size_t)s * HW + off;
        *reinterpret_cast<float4*>(p)     = ot[s];
        *reinterpret_cast<float4*>(p + W) = obt[s];
    }
}

extern "C" void kernel_launch(void* const* d_in, const int* in_sizes, int n_in,
                              void* d_out, int out_size, void* d_ws, size_t ws_size,
                              hipStream_t stream) {
    const float* f = (const float*)d_in[0];
    float* out = (float*)d_out;
    // total threads = 32 batches * 256 coarse rows * 128 float4 cols = 1,048,576
    rg_kernel<<<4096, 256, 0, stream>>>(f, out);
}